// Round 7
// baseline (285.864 us; speedup 1.0000x reference)
//
#include <hip/hip_runtime.h>
#include <hip/hip_bf16.h>
#include <math.h>

// Problem constants
#define Bn 2
#define Sn 2048
#define Dn 1024
#define Hn 16
#define DKn 64

using fragb  = __attribute__((ext_vector_type(8))) short;      // 8 bf16
using frag16 = __attribute__((ext_vector_type(8))) _Float16;   // 8 fp16
using f4     = __attribute__((ext_vector_type(4))) float;

__device__ __forceinline__ short f2bf(float f) {
    union { float f; unsigned u; } v; v.f = f;
    unsigned r = v.u + 0x7FFF + ((v.u >> 16) & 1);   // RNE
    return (short)(r >> 16);
}
__device__ __forceinline__ short f2h(float f) {
    _Float16 h = (_Float16)f;                         // RNE
    short s; __builtin_memcpy(&s, &h, 2); return s;
}

// async global->LDS, 16B per lane; LDS dest = wave-uniform base + lane*16
#define GLOAD(gptr, lptr)                                                     \
    __builtin_amdgcn_global_load_lds(                                         \
        (const __attribute__((address_space(1))) unsigned int*)(const void*)(gptr), \
        (__attribute__((address_space(3))) unsigned int*)(void*)(lptr), 16, 0, 0)

// ---------------- prep: fp32 -> fp16 casts + bf16 mask row ----------------
#define NX (Bn * Sn * Dn)      // 4M
#define NW (Dn * Dn)           // 1M

__global__ __launch_bounds__(256) void prep(
    const float* __restrict__ x,  const float* __restrict__ Wq,
    const float* __restrict__ Wk, const float* __restrict__ Wv,
    const float* __restrict__ Wo, const int* __restrict__ mask,
    short* __restrict__ xh,
    short* __restrict__ Wqh, short* __restrict__ Wkh,
    short* __restrict__ Wvh, short* __restrict__ Woh,
    short* __restrict__ mfb)
{
    int i = blockIdx.x * 256 + threadIdx.x;
    const float* src; short* dst; int j;
    if (i < NX)               { src = x;  dst = xh;  j = i; }
    else if (i < NX + NW)     { src = Wq; dst = Wqh; j = i - NX; }
    else if (i < NX + 2 * NW) { src = Wk; dst = Wkh; j = i - NX - NW; }
    else if (i < NX + 3 * NW) { src = Wv; dst = Wvh; j = i - NX - 2 * NW; }
    else if (i < NX + 4 * NW) { src = Wo; dst = Woh; j = i - NX - 3 * NW; }
    else {
        j = i - NX - 4 * NW;
        if (j < Bn * Sn) mfb[j] = mask[j] ? (short)0x3F80 : (short)0;  // bf16 1/0
        return;
    }
    dst[j] = f2h(src[j]);
}

// ---------------- fp16 single-pass MFMA GEMM ----------------
#define BN 128
#define BK 32

template <int BMT>
__global__ __launch_bounds__(256) void gemm_mfma(
    const short* __restrict__ A,
    const short* __restrict__ W0, const float* __restrict__ b0,
    const short* __restrict__ W1, const float* __restrict__ b1,
    const short* __restrict__ W2, const float* __restrict__ b2,
    const int* __restrict__ mask,
    short* __restrict__ Qb, short* __restrict__ Kb, short* __restrict__ Vtb,
    float* __restrict__ outf, int mode)
{
    constexpr int MI = BMT / 32;
    __shared__ __align__(16) short As[BMT * BK];
    __shared__ __align__(16) short Bs[BN * BK];

    const int tid  = threadIdx.x;
    const int wave = tid >> 6;
    const int lane = tid & 63;
    const int quad = lane >> 4;
    const int l16  = lane & 15;
    const int wm   = wave >> 1;
    const int wn   = wave & 1;

    const int m0   = blockIdx.y * BMT;
    const int n0   = blockIdx.x * BN;
    const int widx = n0 >> 10;
    const int nl0  = n0 & 1023;

    const short* Wp   = widx == 0 ? W0 : (widx == 1 ? W1 : W2);
    const float* bias = widx == 0 ? b0 : (widx == 1 ? b1 : b2);

    f4 acc[MI][4];
    #pragma unroll
    for (int i = 0; i < MI; i++)
        #pragma unroll
        for (int j = 0; j < 4; j++) {
            acc[i][j][0] = 0.f; acc[i][j][1] = 0.f;
            acc[i][j][2] = 0.f; acc[i][j][3] = 0.f;
        }

    const int K = Dn;
    const int lrow = tid >> 2;
    const int lkc  = ((tid & 3) ^ ((tid >> 4) & 3)) * 8;
    const short* Ar = A  + (size_t)(m0  + lrow) * K + lkc;
    const short* Br = Wp + (size_t)(nl0 + lrow) * K + lkc;

    const int sw = (l16 >> 2) & 3;
    const int ca = ((quad ^ sw) * 8);

    for (int k0 = 0; k0 < K; k0 += BK) {
        __syncthreads();
        GLOAD(Ar + k0, &As[wave * 512]);
        if constexpr (BMT == 128)
            GLOAD(Ar + (size_t)64 * K + k0, &As[2048 + wave * 512]);
        GLOAD(Br + k0, &Bs[wave * 512]);
        GLOAD(Br + (size_t)64 * K + k0, &Bs[2048 + wave * 512]);
        __syncthreads();

        frag16 a[MI], b[4];
        #pragma unroll
        for (int mi = 0; mi < MI; mi++)
            a[mi] = *(const frag16*)&As[(wm * (BMT / 2) + mi * 16 + l16) * BK + ca];
        #pragma unroll
        for (int ni = 0; ni < 4; ni++)
            b[ni] = *(const frag16*)&Bs[(wn * 64 + ni * 16 + l16) * BK + ca];
        #pragma unroll
        for (int mi = 0; mi < MI; mi++)
            #pragma unroll
            for (int ni = 0; ni < 4; ni++)
                acc[mi][ni] = __builtin_amdgcn_mfma_f32_16x16x32_f16(
                    a[mi], b[ni], acc[mi][ni], 0, 0, 0);
    }

    const float QSCALE = 0.125f * 1.44269504088896340736f;

    #pragma unroll
    for (int mi = 0; mi < MI; mi++) {
        #pragma unroll
        for (int ni = 0; ni < 4; ni++) {
            int nl = nl0 + wn * 64 + ni * 16 + l16;
            float bv = bias[nl];
            #pragma unroll
            for (int r = 0; r < 4; r++) {
                int m = m0 + wm * (BMT / 2) + mi * 16 + quad * 4 + r;
                float v = acc[mi][ni][r] + bv;
                if (mode == 0) {
                    int b  = m >> 11, s = m & (Sn - 1);
                    int h  = nl >> 6, dk = nl & 63;
                    if (widx == 0)
                        Qb[((size_t)(b * Hn + h) * Sn + s) * DKn + dk] = f2bf(v * QSCALE);
                    else if (widx == 1)
                        Kb[((size_t)(b * Hn + h) * Sn + s) * DKn + dk] = f2bf(v);
                    else {
                        float mv = (float)mask[b * Sn + s];
                        Vtb[((size_t)(b * Hn + h) * DKn + dk) * Sn + s] = f2bf(v * mv);
                    }
                } else {
                    outf[(size_t)m * Dn + nl] = v;
                }
            }
        }
    }
}

// ---------------- Flash attention v4: register-direct K/V, no barriers ------
// Block = 4 independent waves, 128 q-rows (32/wave, 2 q-groups).
// K/V/mask fragments loaded straight from global (coalesced dwordx4, L2-hot);
// LDS used ONLY for the per-wave P C-layout -> A-layout round-trip.
#define LP  72

__global__ __launch_bounds__(256) void attn_mfma(
    const short* __restrict__ Qb, const short* __restrict__ Kb,
    const short* __restrict__ Vtb, const short* __restrict__ mfb,
    short* __restrict__ ctxh)
{
    __shared__ short Ps[4][32 * LP];

    const int tid  = threadIdx.x;
    const int wave = tid >> 6;
    const int lane = tid & 63;
    const int quad = lane >> 4;
    const int l16  = lane & 15;

    const int qt  = blockIdx.x & 15;      // Sn/128 q-tiles
    const int bhh = blockIdx.x >> 4;
    const int b   = bhh >> 4;
    const int h   = bhh & 15;

    // Q fragments: 2 q-groups of 16 rows per wave
    fragb qf[2][2];
    #pragma unroll
    for (int w = 0; w < 2; w++) {
        int qrow = qt * 128 + wave * 32 + w * 16 + l16;
        const short* qptr = Qb + ((size_t)bhh * Sn + qrow) * DKn + quad * 8;
        qf[w][0] = *(const fragb*)(qptr);
        qf[w][1] = *(const fragb*)(qptr + 32);
    }

    f4 ctx[2][4];
    #pragma unroll
    for (int w = 0; w < 2; w++)
        #pragma unroll
        for (int dt = 0; dt < 4; dt++) {
            ctx[w][dt][0] = 0.f; ctx[w][dt][1] = 0.f;
            ctx[w][dt][2] = 0.f; ctx[w][dt][3] = 0.f;
        }
    f4 lacc[2];
    lacc[0][0] = 0.f; lacc[0][1] = 0.f; lacc[0][2] = 0.f; lacc[0][3] = 0.f;
    lacc[1] = lacc[0];

    const short* Kg = Kb  + (size_t)bhh * Sn * DKn;
    const short* Vg = Vtb + (size_t)bhh * DKn * Sn;
    const short* mg = mfb + (size_t)b * Sn;

    // per-lane base addresses for frag loads
    const short* Kl = Kg + (size_t)l16 * DKn + quad * 8;          // + t*16*64 + kt*4096
    const short* Vl = Vg + (size_t)l16 * Sn + quad * 8;           // + dt*16*Sn + kt*64
    const short* ml = mg + quad * 8;                              // + kt*64

    for (int kt = 0; kt < Sn / 64; kt++) {
        // ---- K / V / mask fragments straight from global (L2-hot)
        fragb kf[4][2], vf[4][2];
        #pragma unroll
        for (int t = 0; t < 4; t++) {
            const short* p = Kl + (size_t)kt * 4096 + t * 16 * DKn;
            kf[t][0] = *(const fragb*)(p);
            kf[t][1] = *(const fragb*)(p + 32);
        }
        #pragma unroll
        for (int dt = 0; dt < 4; dt++) {
            const short* p = Vl + (size_t)dt * 16 * Sn + kt * 64;
            vf[dt][0] = *(const fragb*)(p);
            vf[dt][1] = *(const fragb*)(p + 32);
        }
        fragb mf0 = *(const fragb*)(ml + kt * 64);
        fragb mf1 = *(const fragb*)(ml + kt * 64 + 32);

        // ---- S^T: per t, K frags shared across both q-groups
        #pragma unroll
        for (int t = 0; t < 4; t++) {
            #pragma unroll
            for (int w = 0; w < 2; w++) {
                f4 a; a[0] = 0.f; a[1] = 0.f; a[2] = 0.f; a[3] = 0.f;
                a = __builtin_amdgcn_mfma_f32_16x16x32_bf16(kf[t][0], qf[w][0], a, 0, 0, 0);
                a = __builtin_amdgcn_mfma_f32_16x16x32_bf16(kf[t][1], qf[w][1], a, 0, 0, 0);
                unsigned u0 = __float_as_uint(exp2f(a[0]));
                unsigned u1 = __float_as_uint(exp2f(a[1]));
                unsigned u2 = __float_as_uint(exp2f(a[2]));
                unsigned u3 = __float_as_uint(exp2f(a[3]));
                uint2 pw;
                pw.x = __builtin_amdgcn_perm(u1, u0, 0x07060302u);
                pw.y = __builtin_amdgcn_perm(u3, u2, 0x07060302u);
                *(uint2*)&Ps[wave][(w * 16 + l16) * LP + 16 * t + quad * 4] = pw;
            }
        }

        // ---- P frags (per-wave LDS round-trip), then PV + l
        fragb p[2][2];
        #pragma unroll
        for (int w = 0; w < 2; w++) {
            p[w][0] = *(const fragb*)&Ps[wave][(w * 16 + l16) * LP + quad * 8];
            p[w][1] = *(const fragb*)&Ps[wave][(w * 16 + l16) * LP + quad * 8 + 32];
        }
        #pragma unroll
        for (int w = 0; w < 2; w++) {
            lacc[w] = __builtin_amdgcn_mfma_f32_16x16x32_bf16(p[w][0], mf0, lacc[w], 0, 0, 0);
            lacc[w] = __builtin_amdgcn_mfma_f32_16x16x32_bf16(p[w][1], mf1, lacc[w], 0, 0, 0);
        }
        #pragma unroll
        for (int dt = 0; dt < 4; dt++)
            #pragma unroll
            for (int w = 0; w < 2; w++) {
                ctx[w][dt] = __builtin_amdgcn_mfma_f32_16x16x32_bf16(p[w][0], vf[dt][0], ctx[w][dt], 0, 0, 0);
                ctx[w][dt] = __builtin_amdgcn_mfma_f32_16x16x32_bf16(p[w][1], vf[dt][1], ctx[w][dt], 0, 0, 0);
            }
    }

    // ---- epilogue
    #pragma unroll
    for (int w = 0; w < 2; w++)
        #pragma unroll
        for (int r = 0; r < 4; r++) {
            float inv = 1.f / lacc[w][r];
            int row = qt * 128 + wave * 32 + w * 16 + quad * 4 + r;
            #pragma unroll
            for (int dt = 0; dt < 4; dt++) {
                float val = ctx[w][dt][r] * inv;
                size_t idx = ((size_t)(b * Sn + row)) * Dn + h * DKn + dt * 16 + l16;
                ctxh[idx] = f2h(val);
            }
        }
}

// ---------------- launch ----------------
extern "C" void kernel_launch(void* const* d_in, const int* in_sizes, int n_in,
                              void* d_out, int out_size, void* d_ws, size_t ws_size,
                              hipStream_t stream) {
    const float* x    = (const float*)d_in[0];
    const int*   mask = (const int*)d_in[1];
    const float* Wq   = (const float*)d_in[2];
    const float* bq   = (const float*)d_in[3];
    const float* Wk   = (const float*)d_in[4];
    const float* bk   = (const float*)d_in[5];
    const float* Wv   = (const float*)d_in[6];
    const float* bv   = (const float*)d_in[7];
    const float* Wo   = (const float*)d_in[8];
    const float* bo   = (const float*)d_in[9];
    float* out = (float*)d_out;

    char* ws = (char*)d_ws;
    const size_t MB = 1024u * 1024u;
    short* xh  = (short*)(ws + 0 * MB);
    short* Wqh = (short*)(ws + 8 * MB);
    short* Wkh = (short*)(ws + 10 * MB);
    short* Wvh = (short*)(ws + 12 * MB);
    short* Woh = (short*)(ws + 14 * MB);
    short* Qb  = (short*)(ws + 16 * MB);
    short* Kb  = (short*)(ws + 24 * MB);
    short* Vtb = (short*)(ws + 32 * MB);
    short* Ch  = (short*)(ws + 40 * MB);
    short* mfb = (short*)(ws + 48 * MB);

    const int TOT = NX + 4 * NW + Bn * Sn;
    prep<<<(TOT + 255) / 256, 256, 0, stream>>>(
        x, Wq, Wk, Wv, Wo, mask, xh, Wqh, Wkh, Wvh, Woh, mfb);

    gemm_mfma<128><<<dim3(24, 32), 256, 0, stream>>>(
        xh, Wqh, bq, Wkh, bk, Wvh, bv, mask,
        Qb, Kb, Vtb, nullptr, 0);

    attn_mfma<<<dim3(Bn * Hn * (Sn / 128)), 256, 0, stream>>>(
        Qb, Kb, Vtb, mfb, Ch);

    gemm_mfma<64><<<dim3(8, 64), 256, 0, stream>>>(
        Ch, Woh, bo, Woh, bo, Woh, bo, mask,
        nullptr, nullptr, nullptr, out, 1);
}

// Round 8
// 228.132 us; speedup vs baseline: 1.2531x; 1.2531x over previous
//
#include <hip/hip_runtime.h>
#include <hip/hip_bf16.h>
#include <math.h>

// Problem constants
#define Bn 2
#define Sn 2048
#define Dn 1024
#define Hn 16
#define DKn 64

using fragb  = __attribute__((ext_vector_type(8))) short;      // 8 bf16
using frag16 = __attribute__((ext_vector_type(8))) _Float16;   // 8 fp16
using f4     = __attribute__((ext_vector_type(4))) float;

__device__ __forceinline__ short f2bf(float f) {
    union { float f; unsigned u; } v; v.f = f;
    unsigned r = v.u + 0x7FFF + ((v.u >> 16) & 1);   // RNE
    return (short)(r >> 16);
}
__device__ __forceinline__ short f2h(float f) {
    _Float16 h = (_Float16)f;                         // RNE
    short s; __builtin_memcpy(&s, &h, 2); return s;
}

// async global->LDS, 16B per lane; LDS dest = wave-uniform base + lane*16
#define GLOAD(gptr, lptr)                                                     \
    __builtin_amdgcn_global_load_lds(                                         \
        (const __attribute__((address_space(1))) unsigned int*)(const void*)(gptr), \
        (__attribute__((address_space(3))) unsigned int*)(void*)(lptr), 16, 0, 0)

// ---------------- prep: fp32 -> fp16 casts + bf16 mask row ----------------
#define NX (Bn * Sn * Dn)      // 4M
#define NW (Dn * Dn)           // 1M

__global__ __launch_bounds__(256) void prep(
    const float* __restrict__ x,  const float* __restrict__ Wq,
    const float* __restrict__ Wk, const float* __restrict__ Wv,
    const float* __restrict__ Wo, const int* __restrict__ mask,
    short* __restrict__ xh,
    short* __restrict__ Wqh, short* __restrict__ Wkh,
    short* __restrict__ Wvh, short* __restrict__ Woh,
    short* __restrict__ mfb)
{
    int i = blockIdx.x * 256 + threadIdx.x;
    const float* src; short* dst; int j;
    if (i < NX)               { src = x;  dst = xh;  j = i; }
    else if (i < NX + NW)     { src = Wq; dst = Wqh; j = i - NX; }
    else if (i < NX + 2 * NW) { src = Wk; dst = Wkh; j = i - NX - NW; }
    else if (i < NX + 3 * NW) { src = Wv; dst = Wvh; j = i - NX - 2 * NW; }
    else if (i < NX + 4 * NW) { src = Wo; dst = Woh; j = i - NX - 3 * NW; }
    else {
        j = i - NX - 4 * NW;
        if (j < Bn * Sn) mfb[j] = mask[j] ? (short)0x3F80 : (short)0;  // bf16 1/0
        return;
    }
    dst[j] = f2h(src[j]);
}

// ---------------- fp16 single-pass MFMA GEMM, BK=64 ----------------
// C[M][Ntot] = A[M][K]*W[Ntot][K]^T + bias (fp32 accumulate in MFMA).
// BK=64: row stride 128B == bank period, so swizzle chunk' = chunk ^ (row&7)
// (staged via per-lane GLOAD source offset; read side applies same xor).
// mode 0 epilogue: widx 0 -> Q bf16 (x 0.125*log2e), 1 -> K bf16, 2 -> V^T (masked)
// mode 1 epilogue: fp32 row-major
#define BN 128
#define BK 64

template <int BMT>
__global__ __launch_bounds__(256) void gemm_mfma(
    const short* __restrict__ A,
    const short* __restrict__ W0, const float* __restrict__ b0,
    const short* __restrict__ W1, const float* __restrict__ b1,
    const short* __restrict__ W2, const float* __restrict__ b2,
    const int* __restrict__ mask,
    short* __restrict__ Qb, short* __restrict__ Kb, short* __restrict__ Vtb,
    float* __restrict__ outf, int mode)
{
    constexpr int MI = BMT / 32;
    __shared__ __align__(16) short As[BMT * BK];
    __shared__ __align__(16) short Bs[BN * BK];

    const int tid  = threadIdx.x;
    const int wave = tid >> 6;
    const int lane = tid & 63;
    const int quad = lane >> 4;
    const int l16  = lane & 15;
    const int wm   = wave >> 1;
    const int wn   = wave & 1;

    const int m0   = blockIdx.y * BMT;
    const int n0   = blockIdx.x * BN;
    const int widx = n0 >> 10;
    const int nl0  = n0 & 1023;

    const short* Wp   = widx == 0 ? W0 : (widx == 1 ? W1 : W2);
    const float* bias = widx == 0 ? b0 : (widx == 1 ? b1 : b2);

    f4 acc[MI][4];
    #pragma unroll
    for (int i = 0; i < MI; i++)
        #pragma unroll
        for (int j = 0; j < 4; j++) {
            acc[i][j][0] = 0.f; acc[i][j][1] = 0.f;
            acc[i][j][2] = 0.f; acc[i][j][3] = 0.f;
        }

    const int K = Dn;
    // staging: one wave-GLOAD covers 8 rows x 64 shorts; lane l -> row l/8,
    // source chunk (l%8)^(l/8) so LDS lands XOR-swizzled
    const int lr = lane >> 3;
    const int sc = ((lane & 7) ^ lr) * 8;
    const short* Apl = A  + (size_t)(m0  + lr) * K + sc;
    const short* Bpl = Wp + (size_t)(nl0 + lr) * K + sc;

    // read-side swizzled chunk offsets (shorts): chunk = ki*4+quad, xor row&7
    const int ca0 = ((quad ^ (l16 & 7)) * 8);
    const int ca1 = (((quad + 4) ^ (l16 & 7)) * 8);

    for (int k0 = 0; k0 < K; k0 += BK) {
        __syncthreads();
        if constexpr (BMT == 128) {
            #pragma unroll
            for (int g = 0; g < 4; g++)
                GLOAD(Apl + (size_t)(wave * 32 + g * 8) * K + k0,
                      &As[(wave * 32 + g * 8) * BK]);
        } else {
            #pragma unroll
            for (int g = 0; g < 2; g++)
                GLOAD(Apl + (size_t)(wave * 16 + g * 8) * K + k0,
                      &As[(wave * 16 + g * 8) * BK]);
        }
        #pragma unroll
        for (int g = 0; g < 4; g++)
            GLOAD(Bpl + (size_t)(wave * 32 + g * 8) * K + k0,
                  &Bs[(wave * 32 + g * 8) * BK]);
        __syncthreads();

        #pragma unroll
        for (int ki = 0; ki < 2; ki++) {
            const int ca = ki ? ca1 : ca0;
            frag16 a[MI], b[4];
            #pragma unroll
            for (int mi = 0; mi < MI; mi++)
                a[mi] = *(const frag16*)&As[(wm * (BMT / 2) + mi * 16 + l16) * BK + ca];
            #pragma unroll
            for (int ni = 0; ni < 4; ni++)
                b[ni] = *(const frag16*)&Bs[(wn * 64 + ni * 16 + l16) * BK + ca];
            #pragma unroll
            for (int mi = 0; mi < MI; mi++)
                #pragma unroll
                for (int ni = 0; ni < 4; ni++)
                    acc[mi][ni] = __builtin_amdgcn_mfma_f32_16x16x32_f16(
                        a[mi], b[ni], acc[mi][ni], 0, 0, 0);
        }
    }

    const float QSCALE = 0.125f * 1.44269504088896340736f;

    #pragma unroll
    for (int mi = 0; mi < MI; mi++) {
        #pragma unroll
        for (int ni = 0; ni < 4; ni++) {
            int nl = nl0 + wn * 64 + ni * 16 + l16;
            float bv = bias[nl];
            #pragma unroll
            for (int r = 0; r < 4; r++) {
                int m = m0 + wm * (BMT / 2) + mi * 16 + quad * 4 + r;
                float v = acc[mi][ni][r] + bv;
                if (mode == 0) {
                    int b  = m >> 11, s = m & (Sn - 1);
                    int h  = nl >> 6, dk = nl & 63;
                    if (widx == 0)
                        Qb[((size_t)(b * Hn + h) * Sn + s) * DKn + dk] = f2bf(v * QSCALE);
                    else if (widx == 1)
                        Kb[((size_t)(b * Hn + h) * Sn + s) * DKn + dk] = f2bf(v);
                    else {
                        float mv = (float)mask[b * Sn + s];
                        Vtb[((size_t)(b * Hn + h) * DKn + dk) * Sn + s] = f2bf(v * mv);
                    }
                } else {
                    outf[(size_t)m * Dn + nl] = v;
                }
            }
        }
    }
}

// ---------------- Flash attention (R6 kernel): 2 q-groups/wave, GLOAD+swizzle
#define LP  72

__global__ __launch_bounds__(256) void attn_mfma(
    const short* __restrict__ Qb, const short* __restrict__ Kb,
    const short* __restrict__ Vtb, const short* __restrict__ mfb,
    short* __restrict__ ctxh)
{
    __shared__ __align__(16) short Ks[64 * 64];
    __shared__ __align__(16) short Vs[64 * 64];
    __shared__ short Ps[4][32 * LP];
    __shared__ __align__(16) short mfs[64];

    const int tid  = threadIdx.x;
    const int wave = tid >> 6;
    const int lane = tid & 63;
    const int quad = lane >> 4;
    const int l16  = lane & 15;

    const int qt  = blockIdx.x & 15;      // Sn/128 q-tiles
    const int bhh = blockIdx.x >> 4;
    const int b   = bhh >> 4;
    const int h   = bhh & 15;

    fragb qf[2][2];
    #pragma unroll
    for (int w = 0; w < 2; w++) {
        int qrow = qt * 128 + wave * 32 + w * 16 + l16;
        const short* qptr = Qb + ((size_t)bhh * Sn + qrow) * DKn + quad * 8;
        qf[w][0] = *(const fragb*)(qptr);
        qf[w][1] = *(const fragb*)(qptr + 32);
    }

    f4 ctx[2][4];
    #pragma unroll
    for (int w = 0; w < 2; w++)
        #pragma unroll
        for (int dt = 0; dt < 4; dt++) {
            ctx[w][dt][0] = 0.f; ctx[w][dt][1] = 0.f;
            ctx[w][dt][2] = 0.f; ctx[w][dt][3] = 0.f;
        }
    f4 lacc[2];
    lacc[0][0] = 0.f; lacc[0][1] = 0.f; lacc[0][2] = 0.f; lacc[0][3] = 0.f;
    lacc[1] = lacc[0];

    const int lr = lane >> 3;
    const int sc = ((lane & 7) ^ lr) * 8;
    const short* Kg = Kb  + (size_t)bhh * Sn * DKn;
    const short* Vg = Vtb + (size_t)bhh * DKn * Sn;
    const short* mg = mfb + (size_t)b * Sn;

    const short* Ksrc = Kg + (size_t)(wave * 16 + lr) * DKn + sc;
    const short* Vsrc = Vg + (size_t)(wave * 16 + lr) * Sn + sc;

    const int c0 = ((quad ^ (l16 & 7)) * 8);

    for (int kt = 0; kt < Sn / 64; kt++) {
        __syncthreads();
        GLOAD(Ksrc + (size_t)kt * 4096,             &Ks[(wave * 16) * 64]);
        GLOAD(Ksrc + (size_t)kt * 4096 + 8 * DKn,   &Ks[(wave * 16 + 8) * 64]);
        GLOAD(Vsrc + (size_t)kt * 64,               &Vs[(wave * 16) * 64]);
        GLOAD(Vsrc + (size_t)kt * 64 + 8 * Sn,      &Vs[(wave * 16 + 8) * 64]);
        if (tid < 8)
            *(uint4*)&mfs[tid * 8] = *(const uint4*)(mg + kt * 64 + tid * 8);
        __syncthreads();

        // ---- S^T: per t, K frags shared across both q-groups
        #pragma unroll
        for (int t = 0; t < 4; t++) {
            fragb k0 = *(const fragb*)&Ks[(t * 16 + l16) * 64 + c0];
            fragb k1 = *(const fragb*)&Ks[(t * 16 + l16) * 64 + (c0 ^ 32)];
            #pragma unroll
            for (int w = 0; w < 2; w++) {
                f4 a; a[0] = 0.f; a[1] = 0.f; a[2] = 0.f; a[3] = 0.f;
                a = __builtin_amdgcn_mfma_f32_16x16x32_bf16(k0, qf[w][0], a, 0, 0, 0);
                a = __builtin_amdgcn_mfma_f32_16x16x32_bf16(k1, qf[w][1], a, 0, 0, 0);
                unsigned u0 = __float_as_uint(exp2f(a[0]));
                unsigned u1 = __float_as_uint(exp2f(a[1]));
                unsigned u2 = __float_as_uint(exp2f(a[2]));
                unsigned u3 = __float_as_uint(exp2f(a[3]));
                uint2 pw;
                pw.x = __builtin_amdgcn_perm(u1, u0, 0x07060302u);
                pw.y = __builtin_amdgcn_perm(u3, u2, 0x07060302u);
                *(uint2*)&Ps[wave][(w * 16 + l16) * LP + 16 * t + quad * 4] = pw;
            }
        }

        // ---- PV + l accumulation (V/mask frags shared across q-groups)
        fragb p[2][2];
        #pragma unroll
        for (int w = 0; w < 2; w++) {
            p[w][0] = *(const fragb*)&Ps[wave][(w * 16 + l16) * LP + quad * 8];
            p[w][1] = *(const fragb*)&Ps[wave][(w * 16 + l16) * LP + quad * 8 + 32];
        }
        fragb m0 = *(const fragb*)&mfs[quad * 8];
        fragb m1 = *(const fragb*)&mfs[quad * 8 + 32];
        #pragma unroll
        for (int w = 0; w < 2; w++) {
            lacc[w] = __builtin_amdgcn_mfma_f32_16x16x32_bf16(p[w][0], m0, lacc[w], 0, 0, 0);
            lacc[w] = __builtin_amdgcn_mfma_f32_16x16x32_bf16(p[w][1], m1, lacc[w], 0, 0, 0);
        }
        #pragma unroll
        for (int dt = 0; dt < 4; dt++) {
            fragb v0 = *(const fragb*)&Vs[(dt * 16 + l16) * 64 + c0];
            fragb v1 = *(const fragb*)&Vs[(dt * 16 + l16) * 64 + (c0 ^ 32)];
            #pragma unroll
            for (int w = 0; w < 2; w++) {
                ctx[w][dt] = __builtin_amdgcn_mfma_f32_16x16x32_bf16(p[w][0], v0, ctx[w][dt], 0, 0, 0);
                ctx[w][dt] = __builtin_amdgcn_mfma_f32_16x16x32_bf16(p[w][1], v1, ctx[w][dt], 0, 0, 0);
            }
        }
    }

    // ---- epilogue
    #pragma unroll
    for (int w = 0; w < 2; w++)
        #pragma unroll
        for (int r = 0; r < 4; r++) {
            float inv = 1.f / lacc[w][r];
            int row = qt * 128 + wave * 32 + w * 16 + quad * 4 + r;
            #pragma unroll
            for (int dt = 0; dt < 4; dt++) {
                float val = ctx[w][dt][r] * inv;
                size_t idx = ((size_t)(b * Sn + row)) * Dn + h * DKn + dt * 16 + l16;
                ctxh[idx] = f2h(val);
            }
        }
}

// ---------------- launch ----------------
extern "C" void kernel_launch(void* const* d_in, const int* in_sizes, int n_in,
                              void* d_out, int out_size, void* d_ws, size_t ws_size,
                              hipStream_t stream) {
    const float* x    = (const float*)d_in[0];
    const int*   mask = (const int*)d_in[1];
    const float* Wq   = (const float*)d_in[2];
    const float* bq   = (const float*)d_in[3];
    const float* Wk   = (const float*)d_in[4];
    const float* bk   = (const float*)d_in[5];
    const float* Wv   = (const float*)d_in[6];
    const float* bv   = (const float*)d_in[7];
    const float* Wo   = (const float*)d_in[8];
    const float* bo   = (const float*)d_in[9];
    float* out = (float*)d_out;

    char* ws = (char*)d_ws;
    const size_t MB = 1024u * 1024u;
    short* xh  = (short*)(ws + 0 * MB);
    short* Wqh = (short*)(ws + 8 * MB);
    short* Wkh = (short*)(ws + 10 * MB);
    short* Wvh = (short*)(ws + 12 * MB);
    short* Woh = (short*)(ws + 14 * MB);
    short* Qb  = (short*)(ws + 16 * MB);
    short* Kb  = (short*)(ws + 24 * MB);
    short* Vtb = (short*)(ws + 32 * MB);
    short* Ch  = (short*)(ws + 40 * MB);
    short* mfb = (short*)(ws + 48 * MB);

    const int TOT = NX + 4 * NW + Bn * Sn;
    prep<<<(TOT + 255) / 256, 256, 0, stream>>>(
        x, Wq, Wk, Wv, Wo, mask, xh, Wqh, Wkh, Wvh, Woh, mfb);

    gemm_mfma<128><<<dim3(24, 32), 256, 0, stream>>>(
        xh, Wqh, bq, Wkh, bk, Wvh, bv, mask,
        Qb, Kb, Vtb, nullptr, 0);

    attn_mfma<<<dim3(Bn * Hn * (Sn / 128)), 256, 0, stream>>>(
        Qb, Kb, Vtb, mfb, Ch);

    gemm_mfma<64><<<dim3(8, 64), 256, 0, stream>>>(
        Ch, Woh, bo, Woh, bo, Woh, bo, mask,
        nullptr, nullptr, nullptr, out, 1);
}

// Round 9
// 225.572 us; speedup vs baseline: 1.2673x; 1.0113x over previous
//
#include <hip/hip_runtime.h>
#include <hip/hip_bf16.h>
#include <math.h>

// Problem constants
#define Bn 2
#define Sn 2048
#define Dn 1024
#define Hn 16
#define DKn 64
#define BHS (Bn * Hn * Sn)

using fragb  = __attribute__((ext_vector_type(8))) short;      // 8 bf16
using frag16 = __attribute__((ext_vector_type(8))) _Float16;   // 8 fp16
using f4     = __attribute__((ext_vector_type(4))) float;

__device__ __forceinline__ short f2bf(float f) {
    union { float f; unsigned u; } v; v.f = f;
    unsigned r = v.u + 0x7FFF + ((v.u >> 16) & 1);   // RNE
    return (short)(r >> 16);
}
__device__ __forceinline__ short f2h(float f) {
    _Float16 h = (_Float16)f;                         // RNE
    short s; __builtin_memcpy(&s, &h, 2); return s;
}

// async global->LDS, 16B per lane; LDS dest = wave-uniform base + lane*16
#define GLOAD(gptr, lptr)                                                     \
    __builtin_amdgcn_global_load_lds(                                         \
        (const __attribute__((address_space(1))) unsigned int*)(const void*)(gptr), \
        (__attribute__((address_space(3))) unsigned int*)(void*)(lptr), 16, 0, 0)

// ---------------- prep: fp32 -> fp16 casts + bf16 mask row ----------------
#define NX (Bn * Sn * Dn)      // 4M
#define NW (Dn * Dn)           // 1M

__global__ __launch_bounds__(256) void prep(
    const float* __restrict__ x,  const float* __restrict__ Wq,
    const float* __restrict__ Wk, const float* __restrict__ Wv,
    const float* __restrict__ Wo, const int* __restrict__ mask,
    short* __restrict__ xh,
    short* __restrict__ Wqh, short* __restrict__ Wkh,
    short* __restrict__ Wvh, short* __restrict__ Woh,
    short* __restrict__ mfb)
{
    int i = blockIdx.x * 256 + threadIdx.x;
    const float* src; short* dst; int j;
    if (i < NX)               { src = x;  dst = xh;  j = i; }
    else if (i < NX + NW)     { src = Wq; dst = Wqh; j = i - NX; }
    else if (i < NX + 2 * NW) { src = Wk; dst = Wkh; j = i - NX - NW; }
    else if (i < NX + 3 * NW) { src = Wv; dst = Wvh; j = i - NX - 2 * NW; }
    else if (i < NX + 4 * NW) { src = Wo; dst = Woh; j = i - NX - 3 * NW; }
    else {
        j = i - NX - 4 * NW;
        if (j < Bn * Sn) mfb[j] = mask[j] ? (short)0x3F80 : (short)0;  // bf16 1/0
        return;
    }
    dst[j] = f2h(src[j]);
}

// ---------------- fp16 single-pass MFMA GEMM, BK=64 ----------------
#define BN 128
#define BK 64

template <int BMT>
__global__ __launch_bounds__(256) void gemm_mfma(
    const short* __restrict__ A,
    const short* __restrict__ W0, const float* __restrict__ b0,
    const short* __restrict__ W1, const float* __restrict__ b1,
    const short* __restrict__ W2, const float* __restrict__ b2,
    const int* __restrict__ mask,
    short* __restrict__ Qb, short* __restrict__ Kb, short* __restrict__ Vtb,
    float* __restrict__ outf, int mode)
{
    constexpr int MI = BMT / 32;
    __shared__ __align__(16) short As[BMT * BK];
    __shared__ __align__(16) short Bs[BN * BK];

    const int tid  = threadIdx.x;
    const int wave = tid >> 6;
    const int lane = tid & 63;
    const int quad = lane >> 4;
    const int l16  = lane & 15;
    const int wm   = wave >> 1;
    const int wn   = wave & 1;

    const int m0   = blockIdx.y * BMT;
    const int n0   = blockIdx.x * BN;
    const int widx = n0 >> 10;
    const int nl0  = n0 & 1023;

    const short* Wp   = widx == 0 ? W0 : (widx == 1 ? W1 : W2);
    const float* bias = widx == 0 ? b0 : (widx == 1 ? b1 : b2);

    f4 acc[MI][4];
    #pragma unroll
    for (int i = 0; i < MI; i++)
        #pragma unroll
        for (int j = 0; j < 4; j++) {
            acc[i][j][0] = 0.f; acc[i][j][1] = 0.f;
            acc[i][j][2] = 0.f; acc[i][j][3] = 0.f;
        }

    const int K = Dn;
    const int lr = lane >> 3;
    const int sc = ((lane & 7) ^ lr) * 8;
    const short* Apl = A  + (size_t)(m0  + lr) * K + sc;
    const short* Bpl = Wp + (size_t)(nl0 + lr) * K + sc;

    const int ca0 = ((quad ^ (l16 & 7)) * 8);
    const int ca1 = (((quad + 4) ^ (l16 & 7)) * 8);

    for (int k0 = 0; k0 < K; k0 += BK) {
        __syncthreads();
        if constexpr (BMT == 128) {
            #pragma unroll
            for (int g = 0; g < 4; g++)
                GLOAD(Apl + (size_t)(wave * 32 + g * 8) * K + k0,
                      &As[(wave * 32 + g * 8) * BK]);
        } else {
            #pragma unroll
            for (int g = 0; g < 2; g++)
                GLOAD(Apl + (size_t)(wave * 16 + g * 8) * K + k0,
                      &As[(wave * 16 + g * 8) * BK]);
        }
        #pragma unroll
        for (int g = 0; g < 4; g++)
            GLOAD(Bpl + (size_t)(wave * 32 + g * 8) * K + k0,
                  &Bs[(wave * 32 + g * 8) * BK]);
        __syncthreads();

        #pragma unroll
        for (int ki = 0; ki < 2; ki++) {
            const int ca = ki ? ca1 : ca0;
            frag16 a[MI], b[4];
            #pragma unroll
            for (int mi = 0; mi < MI; mi++)
                a[mi] = *(const frag16*)&As[(wm * (BMT / 2) + mi * 16 + l16) * BK + ca];
            #pragma unroll
            for (int ni = 0; ni < 4; ni++)
                b[ni] = *(const frag16*)&Bs[(wn * 64 + ni * 16 + l16) * BK + ca];
            #pragma unroll
            for (int mi = 0; mi < MI; mi++)
                #pragma unroll
                for (int ni = 0; ni < 4; ni++)
                    acc[mi][ni] = __builtin_amdgcn_mfma_f32_16x16x32_f16(
                        a[mi], b[ni], acc[mi][ni], 0, 0, 0);
        }
    }

    const float QSCALE = 0.125f * 1.44269504088896340736f;

    #pragma unroll
    for (int mi = 0; mi < MI; mi++) {
        #pragma unroll
        for (int ni = 0; ni < 4; ni++) {
            int nl = nl0 + wn * 64 + ni * 16 + l16;
            float bv = bias[nl];
            #pragma unroll
            for (int r = 0; r < 4; r++) {
                int m = m0 + wm * (BMT / 2) + mi * 16 + quad * 4 + r;
                float v = acc[mi][ni][r] + bv;
                if (mode == 0) {
                    int b  = m >> 11, s = m & (Sn - 1);
                    int h  = nl >> 6, dk = nl & 63;
                    if (widx == 0)
                        Qb[((size_t)(b * Hn + h) * Sn + s) * DKn + dk] = f2bf(v * QSCALE);
                    else if (widx == 1)
                        Kb[((size_t)(b * Hn + h) * Sn + s) * DKn + dk] = f2bf(v);
                    else {
                        float mv = (float)mask[b * Sn + s];
                        Vtb[((size_t)(b * Hn + h) * DKn + dk) * Sn + s] = f2bf(v * mv);
                    }
                } else {
                    outf[(size_t)m * Dn + nl] = v;
                }
            }
        }
    }
}

// ---------------- Flash attention v5: split-K x2 (additive max-free softmax)
// grid = 1024: blockIdx = {bhh, qt, split}. Each block does 16 of 32 k-chunks
// and writes UNNORMALIZED fp32 partial ctx + partial l; partials are purely
// additive because the softmax is max-free. reduce_ctx merges + normalizes.
#define LP  72

__global__ __launch_bounds__(256) void attn_mfma(
    const short* __restrict__ Qb, const short* __restrict__ Kb,
    const short* __restrict__ Vtb, const short* __restrict__ mfb,
    float* __restrict__ ctxp0, float* __restrict__ ctxp1,
    float* __restrict__ lp)
{
    __shared__ __align__(16) short Ks[64 * 64];
    __shared__ __align__(16) short Vs[64 * 64];
    __shared__ short Ps[4][32 * LP];
    __shared__ __align__(16) short mfs[64];

    const int tid  = threadIdx.x;
    const int wave = tid >> 6;
    const int lane = tid & 63;
    const int quad = lane >> 4;
    const int l16  = lane & 15;

    const int split = blockIdx.x & 1;
    const int rest  = blockIdx.x >> 1;
    const int qt  = rest & 15;            // Sn/128 q-tiles
    const int bhh = rest >> 4;
    const int b   = bhh >> 4;
    const int h   = bhh & 15;

    fragb qf[2][2];
    #pragma unroll
    for (int w = 0; w < 2; w++) {
        int qrow = qt * 128 + wave * 32 + w * 16 + l16;
        const short* qptr = Qb + ((size_t)bhh * Sn + qrow) * DKn + quad * 8;
        qf[w][0] = *(const fragb*)(qptr);
        qf[w][1] = *(const fragb*)(qptr + 32);
    }

    f4 ctx[2][4];
    #pragma unroll
    for (int w = 0; w < 2; w++)
        #pragma unroll
        for (int dt = 0; dt < 4; dt++) {
            ctx[w][dt][0] = 0.f; ctx[w][dt][1] = 0.f;
            ctx[w][dt][2] = 0.f; ctx[w][dt][3] = 0.f;
        }
    f4 lacc[2];
    lacc[0][0] = 0.f; lacc[0][1] = 0.f; lacc[0][2] = 0.f; lacc[0][3] = 0.f;
    lacc[1] = lacc[0];

    const int lr = lane >> 3;
    const int sc = ((lane & 7) ^ lr) * 8;
    const short* Kg = Kb  + (size_t)bhh * Sn * DKn;
    const short* Vg = Vtb + (size_t)bhh * DKn * Sn;
    const short* mg = mfb + (size_t)b * Sn;

    const short* Ksrc = Kg + (size_t)(wave * 16 + lr) * DKn + sc;
    const short* Vsrc = Vg + (size_t)(wave * 16 + lr) * Sn + sc;

    const int c0 = ((quad ^ (l16 & 7)) * 8);

    const int kt0 = split * 16;
    for (int kt = kt0; kt < kt0 + 16; kt++) {
        __syncthreads();
        GLOAD(Ksrc + (size_t)kt * 4096,             &Ks[(wave * 16) * 64]);
        GLOAD(Ksrc + (size_t)kt * 4096 + 8 * DKn,   &Ks[(wave * 16 + 8) * 64]);
        GLOAD(Vsrc + (size_t)kt * 64,               &Vs[(wave * 16) * 64]);
        GLOAD(Vsrc + (size_t)kt * 64 + 8 * Sn,      &Vs[(wave * 16 + 8) * 64]);
        if (tid < 8)
            *(uint4*)&mfs[tid * 8] = *(const uint4*)(mg + kt * 64 + tid * 8);
        __syncthreads();

        // ---- S^T: per t, K frags shared across both q-groups
        #pragma unroll
        for (int t = 0; t < 4; t++) {
            fragb k0 = *(const fragb*)&Ks[(t * 16 + l16) * 64 + c0];
            fragb k1 = *(const fragb*)&Ks[(t * 16 + l16) * 64 + (c0 ^ 32)];
            #pragma unroll
            for (int w = 0; w < 2; w++) {
                f4 a; a[0] = 0.f; a[1] = 0.f; a[2] = 0.f; a[3] = 0.f;
                a = __builtin_amdgcn_mfma_f32_16x16x32_bf16(k0, qf[w][0], a, 0, 0, 0);
                a = __builtin_amdgcn_mfma_f32_16x16x32_bf16(k1, qf[w][1], a, 0, 0, 0);
                unsigned u0 = __float_as_uint(exp2f(a[0]));
                unsigned u1 = __float_as_uint(exp2f(a[1]));
                unsigned u2 = __float_as_uint(exp2f(a[2]));
                unsigned u3 = __float_as_uint(exp2f(a[3]));
                uint2 pw;
                pw.x = __builtin_amdgcn_perm(u1, u0, 0x07060302u);
                pw.y = __builtin_amdgcn_perm(u3, u2, 0x07060302u);
                *(uint2*)&Ps[wave][(w * 16 + l16) * LP + 16 * t + quad * 4] = pw;
            }
        }

        // ---- PV + l accumulation
        fragb p[2][2];
        #pragma unroll
        for (int w = 0; w < 2; w++) {
            p[w][0] = *(const fragb*)&Ps[wave][(w * 16 + l16) * LP + quad * 8];
            p[w][1] = *(const fragb*)&Ps[wave][(w * 16 + l16) * LP + quad * 8 + 32];
        }
        fragb m0 = *(const fragb*)&mfs[quad * 8];
        fragb m1 = *(const fragb*)&mfs[quad * 8 + 32];
        #pragma unroll
        for (int w = 0; w < 2; w++) {
            lacc[w] = __builtin_amdgcn_mfma_f32_16x16x32_bf16(p[w][0], m0, lacc[w], 0, 0, 0);
            lacc[w] = __builtin_amdgcn_mfma_f32_16x16x32_bf16(p[w][1], m1, lacc[w], 0, 0, 0);
        }
        #pragma unroll
        for (int dt = 0; dt < 4; dt++) {
            fragb v0 = *(const fragb*)&Vs[(dt * 16 + l16) * 64 + c0];
            fragb v1 = *(const fragb*)&Vs[(dt * 16 + l16) * 64 + (c0 ^ 32)];
            #pragma unroll
            for (int w = 0; w < 2; w++) {
                ctx[w][dt] = __builtin_amdgcn_mfma_f32_16x16x32_bf16(p[w][0], v0, ctx[w][dt], 0, 0, 0);
                ctx[w][dt] = __builtin_amdgcn_mfma_f32_16x16x32_bf16(p[w][1], v1, ctx[w][dt], 0, 0, 0);
            }
        }
    }

    // ---- epilogue: unnormalized fp32 partials
    float* cp  = split ? ctxp1 : ctxp0;
    float* lpp = lp + (size_t)split * BHS;
    #pragma unroll
    for (int w = 0; w < 2; w++)
        #pragma unroll
        for (int r = 0; r < 4; r++) {
            int row = qt * 128 + wave * 32 + w * 16 + quad * 4 + r;
            if (l16 == 0) lpp[(size_t)bhh * Sn + row] = lacc[w][r];
            #pragma unroll
            for (int dt = 0; dt < 4; dt++)
                cp[((size_t)(b * Sn + row)) * Dn + h * DKn + dt * 16 + l16] =
                    ctx[w][dt][r];
        }
}

// ---------------- reduce: merge split partials, normalize, emit fp16 --------
__global__ __launch_bounds__(256) void reduce_ctx(
    const float* __restrict__ c0, const float* __restrict__ c1,
    const float* __restrict__ lp, short* __restrict__ Ch)
{
    int i4 = blockIdx.x * 256 + threadIdx.x;      // float4 index, B*S*D/4 total
    int e    = i4 << 2;
    int brow = e >> 10;                            // b*Sn + row
    int d    = e & 1023;
    int b    = brow >> 11;
    int row  = brow & (Sn - 1);
    int h    = d >> 6;
    size_t li = (size_t)(b * Hn + h) * Sn + row;
    float l = lp[li] + lp[BHS + li];
    float inv = 1.f / l;
    float4 v0 = ((const float4*)c0)[i4];
    float4 v1 = ((const float4*)c1)[i4];
    ushort4 o;
    o.x = (unsigned short)f2h((v0.x + v1.x) * inv);
    o.y = (unsigned short)f2h((v0.y + v1.y) * inv);
    o.z = (unsigned short)f2h((v0.z + v1.z) * inv);
    o.w = (unsigned short)f2h((v0.w + v1.w) * inv);
    ((ushort4*)Ch)[i4] = o;
}

// ---------------- launch ----------------
extern "C" void kernel_launch(void* const* d_in, const int* in_sizes, int n_in,
                              void* d_out, int out_size, void* d_ws, size_t ws_size,
                              hipStream_t stream) {
    const float* x    = (const float*)d_in[0];
    const int*   mask = (const int*)d_in[1];
    const float* Wq   = (const float*)d_in[2];
    const float* bq   = (const float*)d_in[3];
    const float* Wk   = (const float*)d_in[4];
    const float* bk   = (const float*)d_in[5];
    const float* Wv   = (const float*)d_in[6];
    const float* bv   = (const float*)d_in[7];
    const float* Wo   = (const float*)d_in[8];
    const float* bo   = (const float*)d_in[9];
    float* out = (float*)d_out;

    char* ws = (char*)d_ws;
    const size_t MB = 1024u * 1024u;
    // 0-16 MB region: xh/Wqh/Wkh/Wvh live only until QKV gemm, then reused as ctxp0
    short* xh    = (short*)(ws + 0 * MB);    // 8 MB fp16  (dead after QKV)
    short* Wqh   = (short*)(ws + 8 * MB);    // dead after QKV
    short* Wkh   = (short*)(ws + 10 * MB);   // dead after QKV
    short* Wvh   = (short*)(ws + 12 * MB);   // dead after QKV
    short* Qb    = (short*)(ws + 16 * MB);   // 8 MB bf16 (live during attn)
    short* Kb    = (short*)(ws + 24 * MB);
    short* Vtb   = (short*)(ws + 32 * MB);
    float* ctxp0 = (float*)(ws + 0 * MB);    // 16 MB fp32 (overlays dead region)
    float* ctxp1 = (float*)(ws + 40 * MB);   // 16 MB fp32
    short* Woh   = (short*)(ws + 56 * MB);   // 2 MB (kept until final gemm)
    float* lp    = (float*)(ws + 58 * MB);   // 2 x 256 KB
    short* mfb   = (short*)(ws + 59 * MB);   // bf16 mask row
    short* Ch    = (short*)(ws + 60 * MB);   // 8 MB fp16 ctx

    const int TOT = NX + 4 * NW + Bn * Sn;
    prep<<<(TOT + 255) / 256, 256, 0, stream>>>(
        x, Wq, Wk, Wv, Wo, mask, xh, Wqh, Wkh, Wvh, Woh, mfb);

    gemm_mfma<128><<<dim3(24, 32), 256, 0, stream>>>(
        xh, Wqh, bq, Wkh, bk, Wvh, bv, mask,
        Qb, Kb, Vtb, nullptr, 0);

    // split-K x2 attention: 1024 blocks
    attn_mfma<<<dim3(Bn * Hn * (Sn / 128) * 2), 256, 0, stream>>>(
        Qb, Kb, Vtb, mfb, ctxp0, ctxp1, lp);

    reduce_ctx<<<dim3(NX / 4 / 256), 256, 0, stream>>>(ctxp0, ctxp1, lp, Ch);

    gemm_mfma<64><<<dim3(8, 64), 256, 0, stream>>>(
        Ch, Woh, bo, Woh, bo, Woh, bo, mask,
        nullptr, nullptr, nullptr, out, 1);
}

// Round 10
// 223.655 us; speedup vs baseline: 1.2782x; 1.0086x over previous
//
#include <hip/hip_runtime.h>
#include <hip/hip_bf16.h>
#include <math.h>

// Problem constants
#define Bn 2
#define Sn 2048
#define Dn 1024
#define Hn 16
#define DKn 64
#define BHS (Bn * Hn * Sn)

using fragb  = __attribute__((ext_vector_type(8))) short;      // 8 bf16
using frag16 = __attribute__((ext_vector_type(8))) _Float16;   // 8 fp16
using f4     = __attribute__((ext_vector_type(4))) float;

__device__ __forceinline__ short f2bf(float f) {
    union { float f; unsigned u; } v; v.f = f;
    unsigned r = v.u + 0x7FFF + ((v.u >> 16) & 1);   // RNE
    return (short)(r >> 16);
}
__device__ __forceinline__ unsigned short f2h(float f) {
    _Float16 h = (_Float16)f;                         // RNE
    unsigned short s; __builtin_memcpy(&s, &h, 2); return s;
}

// async global->LDS, 16B per lane; LDS dest = wave-uniform base + lane*16
#define GLOAD(gptr, lptr)                                                     \
    __builtin_amdgcn_global_load_lds(                                         \
        (const __attribute__((address_space(1))) unsigned int*)(const void*)(gptr), \
        (__attribute__((address_space(3))) unsigned int*)(void*)(lptr), 16, 0, 0)

// ---------------- prep: fp32 -> fp16 casts (x4 vectorized) + bf16 mask row --
#define NX (Bn * Sn * Dn)      // 4M
#define NW (Dn * Dn)           // 1M
#define NF4 ((NX + 4 * NW) / 4)

__global__ __launch_bounds__(256) void prep(
    const float* __restrict__ x,  const float* __restrict__ Wq,
    const float* __restrict__ Wk, const float* __restrict__ Wv,
    const float* __restrict__ Wo, const int* __restrict__ mask,
    short* __restrict__ xh,
    short* __restrict__ Wqh, short* __restrict__ Wkh,
    short* __restrict__ Wvh, short* __restrict__ Woh,
    short* __restrict__ mfb)
{
    int i = blockIdx.x * 256 + threadIdx.x;
    if (i < NF4) {
        int e = i << 2;
        const float* src; short* dst; int j;
        if (e < NX)               { src = x;  dst = xh;  j = e; }
        else if (e < NX + NW)     { src = Wq; dst = Wqh; j = e - NX; }
        else if (e < NX + 2 * NW) { src = Wk; dst = Wkh; j = e - NX - NW; }
        else if (e < NX + 3 * NW) { src = Wv; dst = Wvh; j = e - NX - 2 * NW; }
        else                      { src = Wo; dst = Woh; j = e - NX - 3 * NW; }
        float4 v = *(const float4*)(src + j);
        ushort4 o;
        o.x = f2h(v.x); o.y = f2h(v.y); o.z = f2h(v.z); o.w = f2h(v.w);
        *(ushort4*)(dst + j) = o;
    } else {
        int j = (i - NF4) << 2;
        if (j < Bn * Sn) {
            int4 m = *(const int4*)(mask + j);
            ushort4 o;
            o.x = m.x ? 0x3F80 : 0; o.y = m.y ? 0x3F80 : 0;
            o.z = m.z ? 0x3F80 : 0; o.w = m.w ? 0x3F80 : 0;
            *(ushort4*)(mfb + j) = o;
        }
    }
}

// ---------------- QKV GEMM: fp16, R4-proven structure (BK=32, no swizzle) ---
// C[M][3072] = A[M][1024]*W[n][1024]^T + bias; epilogue by widx:
//   0 -> Q bf16 (x 0.125*log2e), 1 -> K bf16, 2 -> V^T bf16 (masked)
__global__ __launch_bounds__(256) void gemm_qkv(
    const short* __restrict__ A,
    const short* __restrict__ W0, const float* __restrict__ b0,
    const short* __restrict__ W1, const float* __restrict__ b1,
    const short* __restrict__ W2, const float* __restrict__ b2,
    const int* __restrict__ mask,
    short* __restrict__ Qb, short* __restrict__ Kb, short* __restrict__ Vtb)
{
    __shared__ __align__(16) short As[128 * 32];
    __shared__ __align__(16) short Bs[128 * 32];

    const int tid  = threadIdx.x;
    const int wave = tid >> 6;
    const int lane = tid & 63;
    const int quad = lane >> 4;
    const int l16  = lane & 15;
    const int wm   = wave >> 1;
    const int wn   = wave & 1;

    const int m0   = blockIdx.y * 128;
    const int n0   = blockIdx.x * 128;
    const int widx = n0 >> 10;
    const int nl0  = n0 & 1023;

    const short* Wp   = widx == 0 ? W0 : (widx == 1 ? W1 : W2);
    const float* bias = widx == 0 ? b0 : (widx == 1 ? b1 : b2);

    f4 acc[4][4];
    #pragma unroll
    for (int i = 0; i < 4; i++)
        #pragma unroll
        for (int j = 0; j < 4; j++) {
            acc[i][j][0] = 0.f; acc[i][j][1] = 0.f;
            acc[i][j][2] = 0.f; acc[i][j][3] = 0.f;
        }

    const int K = Dn;
    const int r0  = tid >> 2,         kc0 = (tid & 3) * 8;
    const int r1  = (tid + 256) >> 2;
    const short* Ar0 = A  + (size_t)(m0 + r0) * K + kc0;
    const short* Ar1 = A  + (size_t)(m0 + r1) * K + kc0;
    const short* Br0 = Wp + (size_t)(nl0 + r0) * K + kc0;
    const short* Br1 = Wp + (size_t)(nl0 + r1) * K + kc0;

    for (int k0 = 0; k0 < K; k0 += 32) {
        __syncthreads();
        GLOAD(Ar0 + k0, &As[(wave * 64) * 8]);
        GLOAD(Ar1 + k0, &As[(256 + wave * 64) * 8]);
        GLOAD(Br0 + k0, &Bs[(wave * 64) * 8]);
        GLOAD(Br1 + k0, &Bs[(256 + wave * 64) * 8]);
        __syncthreads();

        frag16 a[4], b[4];
        #pragma unroll
        for (int mi = 0; mi < 4; mi++)
            a[mi] = *(const frag16*)&As[(wm * 64 + mi * 16 + l16) * 32 + quad * 8];
        #pragma unroll
        for (int ni = 0; ni < 4; ni++)
            b[ni] = *(const frag16*)&Bs[(wn * 64 + ni * 16 + l16) * 32 + quad * 8];
        #pragma unroll
        for (int mi = 0; mi < 4; mi++)
            #pragma unroll
            for (int ni = 0; ni < 4; ni++)
                acc[mi][ni] = __builtin_amdgcn_mfma_f32_16x16x32_f16(
                    a[mi], b[ni], acc[mi][ni], 0, 0, 0);
    }

    const float QSCALE = 0.125f * 1.44269504088896340736f;

    #pragma unroll
    for (int mi = 0; mi < 4; mi++) {
        #pragma unroll
        for (int ni = 0; ni < 4; ni++) {
            int nl = nl0 + wn * 64 + ni * 16 + l16;
            float bv = bias[nl];
            #pragma unroll
            for (int r = 0; r < 4; r++) {
                int m = m0 + wm * 64 + mi * 16 + quad * 4 + r;
                float v = acc[mi][ni][r] + bv;
                int b  = m >> 11, s = m & (Sn - 1);
                int h  = nl >> 6, dk = nl & 63;
                if (widx == 0)
                    Qb[((size_t)(b * Hn + h) * Sn + s) * DKn + dk] = f2bf(v * QSCALE);
                else if (widx == 1)
                    Kb[((size_t)(b * Hn + h) * Sn + s) * DKn + dk] = f2bf(v);
                else {
                    float mv = (float)mask[b * Sn + s];
                    Vtb[((size_t)(b * Hn + h) * DKn + dk) * Sn + s] = f2bf(v * mv);
                }
            }
        }
    }
}

// ---------------- Out GEMM: fp16, same structure, BM=64, fp32 out -----------
__global__ __launch_bounds__(256) void gemm_out(
    const short* __restrict__ A, const short* __restrict__ Wp,
    const float* __restrict__ bias, float* __restrict__ outf)
{
    __shared__ __align__(16) short As[64 * 32];
    __shared__ __align__(16) short Bs[128 * 32];

    const int tid  = threadIdx.x;
    const int wave = tid >> 6;
    const int lane = tid & 63;
    const int quad = lane >> 4;
    const int l16  = lane & 15;
    const int wm   = wave >> 1;
    const int wn   = wave & 1;

    const int m0 = blockIdx.y * 64;
    const int n0 = blockIdx.x * 128;

    f4 acc[2][4];
    #pragma unroll
    for (int i = 0; i < 2; i++)
        #pragma unroll
        for (int j = 0; j < 4; j++) {
            acc[i][j][0] = 0.f; acc[i][j][1] = 0.f;
            acc[i][j][2] = 0.f; acc[i][j][3] = 0.f;
        }

    const int K = Dn;
    const int r0  = tid >> 2,         kc0 = (tid & 3) * 8;
    const int r1  = (tid + 256) >> 2;
    const short* Ar0 = A  + (size_t)(m0 + r0) * K + kc0;
    const short* Br0 = Wp + (size_t)(n0 + r0) * K + kc0;
    const short* Br1 = Wp + (size_t)(n0 + r1) * K + kc0;

    for (int k0 = 0; k0 < K; k0 += 32) {
        __syncthreads();
        GLOAD(Ar0 + k0, &As[(wave * 64) * 8]);
        GLOAD(Br0 + k0, &Bs[(wave * 64) * 8]);
        GLOAD(Br1 + k0, &Bs[(256 + wave * 64) * 8]);
        __syncthreads();

        frag16 a[2], b[4];
        #pragma unroll
        for (int mi = 0; mi < 2; mi++)
            a[mi] = *(const frag16*)&As[(wm * 32 + mi * 16 + l16) * 32 + quad * 8];
        #pragma unroll
        for (int ni = 0; ni < 4; ni++)
            b[ni] = *(const frag16*)&Bs[(wn * 64 + ni * 16 + l16) * 32 + quad * 8];
        #pragma unroll
        for (int mi = 0; mi < 2; mi++)
            #pragma unroll
            for (int ni = 0; ni < 4; ni++)
                acc[mi][ni] = __builtin_amdgcn_mfma_f32_16x16x32_f16(
                    a[mi], b[ni], acc[mi][ni], 0, 0, 0);
    }

    #pragma unroll
    for (int mi = 0; mi < 2; mi++) {
        #pragma unroll
        for (int ni = 0; ni < 4; ni++) {
            int nl = n0 + wn * 64 + ni * 16 + l16;
            float bv = bias[nl];
            #pragma unroll
            for (int r = 0; r < 4; r++) {
                int m = m0 + wm * 32 + mi * 16 + quad * 4 + r;
                outf[(size_t)m * Dn + nl] = acc[mi][ni][r] + bv;
            }
        }
    }
}

// ---------------- Flash attention: split-K x2, max-free softmax (R9) --------
#define LP  72

__global__ __launch_bounds__(256) void attn_mfma(
    const short* __restrict__ Qb, const short* __restrict__ Kb,
    const short* __restrict__ Vtb, const short* __restrict__ mfb,
    float* __restrict__ ctxp0, float* __restrict__ ctxp1,
    float* __restrict__ lp)
{
    __shared__ __align__(16) short Ks[64 * 64];
    __shared__ __align__(16) short Vs[64 * 64];
    __shared__ short Ps[4][32 * LP];
    __shared__ __align__(16) short mfs[64];

    const int tid  = threadIdx.x;
    const int wave = tid >> 6;
    const int lane = tid & 63;
    const int quad = lane >> 4;
    const int l16  = lane & 15;

    const int split = blockIdx.x & 1;
    const int rest  = blockIdx.x >> 1;
    const int qt  = rest & 15;
    const int bhh = rest >> 4;
    const int b   = bhh >> 4;
    const int h   = bhh & 15;

    fragb qf[2][2];
    #pragma unroll
    for (int w = 0; w < 2; w++) {
        int qrow = qt * 128 + wave * 32 + w * 16 + l16;
        const short* qptr = Qb + ((size_t)bhh * Sn + qrow) * DKn + quad * 8;
        qf[w][0] = *(const fragb*)(qptr);
        qf[w][1] = *(const fragb*)(qptr + 32);
    }

    f4 ctx[2][4];
    #pragma unroll
    for (int w = 0; w < 2; w++)
        #pragma unroll
        for (int dt = 0; dt < 4; dt++) {
            ctx[w][dt][0] = 0.f; ctx[w][dt][1] = 0.f;
            ctx[w][dt][2] = 0.f; ctx[w][dt][3] = 0.f;
        }
    f4 lacc[2];
    lacc[0][0] = 0.f; lacc[0][1] = 0.f; lacc[0][2] = 0.f; lacc[0][3] = 0.f;
    lacc[1] = lacc[0];

    const int lr = lane >> 3;
    const int sc = ((lane & 7) ^ lr) * 8;
    const short* Kg = Kb  + (size_t)bhh * Sn * DKn;
    const short* Vg = Vtb + (size_t)bhh * DKn * Sn;
    const short* mg = mfb + (size_t)b * Sn;

    const short* Ksrc = Kg + (size_t)(wave * 16 + lr) * DKn + sc;
    const short* Vsrc = Vg + (size_t)(wave * 16 + lr) * Sn + sc;

    const int c0 = ((quad ^ (l16 & 7)) * 8);

    const int kt0 = split * 16;
    for (int kt = kt0; kt < kt0 + 16; kt++) {
        __syncthreads();
        GLOAD(Ksrc + (size_t)kt * 4096,             &Ks[(wave * 16) * 64]);
        GLOAD(Ksrc + (size_t)kt * 4096 + 8 * DKn,   &Ks[(wave * 16 + 8) * 64]);
        GLOAD(Vsrc + (size_t)kt * 64,               &Vs[(wave * 16) * 64]);
        GLOAD(Vsrc + (size_t)kt * 64 + 8 * Sn,      &Vs[(wave * 16 + 8) * 64]);
        if (tid < 8)
            *(uint4*)&mfs[tid * 8] = *(const uint4*)(mg + kt * 64 + tid * 8);
        __syncthreads();

        #pragma unroll
        for (int t = 0; t < 4; t++) {
            fragb k0 = *(const fragb*)&Ks[(t * 16 + l16) * 64 + c0];
            fragb k1 = *(const fragb*)&Ks[(t * 16 + l16) * 64 + (c0 ^ 32)];
            #pragma unroll
            for (int w = 0; w < 2; w++) {
                f4 a; a[0] = 0.f; a[1] = 0.f; a[2] = 0.f; a[3] = 0.f;
                a = __builtin_amdgcn_mfma_f32_16x16x32_bf16(k0, qf[w][0], a, 0, 0, 0);
                a = __builtin_amdgcn_mfma_f32_16x16x32_bf16(k1, qf[w][1], a, 0, 0, 0);
                unsigned u0 = __float_as_uint(exp2f(a[0]));
                unsigned u1 = __float_as_uint(exp2f(a[1]));
                unsigned u2 = __float_as_uint(exp2f(a[2]));
                unsigned u3 = __float_as_uint(exp2f(a[3]));
                uint2 pw;
                pw.x = __builtin_amdgcn_perm(u1, u0, 0x07060302u);
                pw.y = __builtin_amdgcn_perm(u3, u2, 0x07060302u);
                *(uint2*)&Ps[wave][(w * 16 + l16) * LP + 16 * t + quad * 4] = pw;
            }
        }

        fragb p[2][2];
        #pragma unroll
        for (int w = 0; w < 2; w++) {
            p[w][0] = *(const fragb*)&Ps[wave][(w * 16 + l16) * LP + quad * 8];
            p[w][1] = *(const fragb*)&Ps[wave][(w * 16 + l16) * LP + quad * 8 + 32];
        }
        fragb m0 = *(const fragb*)&mfs[quad * 8];
        fragb m1 = *(const fragb*)&mfs[quad * 8 + 32];
        #pragma unroll
        for (int w = 0; w < 2; w++) {
            lacc[w] = __builtin_amdgcn_mfma_f32_16x16x32_bf16(p[w][0], m0, lacc[w], 0, 0, 0);
            lacc[w] = __builtin_amdgcn_mfma_f32_16x16x32_bf16(p[w][1], m1, lacc[w], 0, 0, 0);
        }
        #pragma unroll
        for (int dt = 0; dt < 4; dt++) {
            fragb v0 = *(const fragb*)&Vs[(dt * 16 + l16) * 64 + c0];
            fragb v1 = *(const fragb*)&Vs[(dt * 16 + l16) * 64 + (c0 ^ 32)];
            #pragma unroll
            for (int w = 0; w < 2; w++) {
                ctx[w][dt] = __builtin_amdgcn_mfma_f32_16x16x32_bf16(p[w][0], v0, ctx[w][dt], 0, 0, 0);
                ctx[w][dt] = __builtin_amdgcn_mfma_f32_16x16x32_bf16(p[w][1], v1, ctx[w][dt], 0, 0, 0);
            }
        }
    }

    float* cp  = split ? ctxp1 : ctxp0;
    float* lpp = lp + (size_t)split * BHS;
    #pragma unroll
    for (int w = 0; w < 2; w++)
        #pragma unroll
        for (int r = 0; r < 4; r++) {
            int row = qt * 128 + wave * 32 + w * 16 + quad * 4 + r;
            if (l16 == 0) lpp[(size_t)bhh * Sn + row] = lacc[w][r];
            #pragma unroll
            for (int dt = 0; dt < 4; dt++)
                cp[((size_t)(b * Sn + row)) * Dn + h * DKn + dt * 16 + l16] =
                    ctx[w][dt][r];
        }
}

// ---------------- reduce: merge split partials, normalize, emit fp16 --------
__global__ __launch_bounds__(256) void reduce_ctx(
    const float* __restrict__ c0, const float* __restrict__ c1,
    const float* __restrict__ lp, short* __restrict__ Ch)
{
    int i4 = blockIdx.x * 256 + threadIdx.x;
    int e    = i4 << 2;
    int brow = e >> 10;
    int d    = e & 1023;
    int b    = brow >> 11;
    int row  = brow & (Sn - 1);
    int h    = d >> 6;
    size_t li = (size_t)(b * Hn + h) * Sn + row;
    float l = lp[li] + lp[BHS + li];
    float inv = 1.f / l;
    float4 v0 = ((const float4*)c0)[i4];
    float4 v1 = ((const float4*)c1)[i4];
    ushort4 o;
    o.x = f2h((v0.x + v1.x) * inv);
    o.y = f2h((v0.y + v1.y) * inv);
    o.z = f2h((v0.z + v1.z) * inv);
    o.w = f2h((v0.w + v1.w) * inv);
    ((ushort4*)Ch)[i4] = o;
}

// ---------------- launch ----------------
extern "C" void kernel_launch(void* const* d_in, const int* in_sizes, int n_in,
                              void* d_out, int out_size, void* d_ws, size_t ws_size,
                              hipStream_t stream) {
    const float* x    = (const float*)d_in[0];
    const int*   mask = (const int*)d_in[1];
    const float* Wq   = (const float*)d_in[2];
    const float* bq   = (const float*)d_in[3];
    const float* Wk   = (const float*)d_in[4];
    const float* bk   = (const float*)d_in[5];
    const float* Wv   = (const float*)d_in[6];
    const float* bv   = (const float*)d_in[7];
    const float* Wo   = (const float*)d_in[8];
    const float* bo   = (const float*)d_in[9];
    float* out = (float*)d_out;

    char* ws = (char*)d_ws;
    const size_t MB = 1024u * 1024u;
    short* xh    = (short*)(ws + 0 * MB);    // 8 MB fp16 (dead after QKV)
    short* Wqh   = (short*)(ws + 8 * MB);
    short* Wkh   = (short*)(ws + 10 * MB);
    short* Wvh   = (short*)(ws + 12 * MB);
    short* Qb    = (short*)(ws + 16 * MB);
    short* Kb    = (short*)(ws + 24 * MB);
    short* Vtb   = (short*)(ws + 32 * MB);
    float* ctxp0 = (float*)(ws + 0 * MB);    // overlays dead region
    float* ctxp1 = (float*)(ws + 40 * MB);
    short* Woh   = (short*)(ws + 56 * MB);
    float* lp    = (float*)(ws + 58 * MB);
    short* mfb   = (short*)(ws + 59 * MB);
    short* Ch    = (short*)(ws + 60 * MB);

    const int PRE = NF4 + (Bn * Sn) / 4;
    prep<<<(PRE + 255) / 256, 256, 0, stream>>>(
        x, Wq, Wk, Wv, Wo, mask, xh, Wqh, Wkh, Wvh, Woh, mfb);

    gemm_qkv<<<dim3(24, 32), 256, 0, stream>>>(
        xh, Wqh, bq, Wkh, bk, Wvh, bv, mask, Qb, Kb, Vtb);

    attn_mfma<<<dim3(Bn * Hn * (Sn / 128) * 2), 256, 0, stream>>>(
        Qb, Kb, Vtb, mfb, ctxp0, ctxp1, lp);

    reduce_ctx<<<dim3(NX / 4 / 256), 256, 0, stream>>>(ctxp0, ctxp1, lp, Ch);

    gemm_out<<<dim3(8, 64), 256, 0, stream>>>(Ch, Woh, bo, out);
}